// Round 16
// baseline (216.018 us; speedup 1.0000x reference)
//
#include <hip/hip_runtime.h>
#include <math.h>

typedef __bf16 bf16_t;
typedef bf16_t bf16x2 __attribute__((ext_vector_type(2)));
typedef bf16_t bf16x4 __attribute__((ext_vector_type(4)));
typedef bf16_t bf16x8 __attribute__((ext_vector_type(8)));
typedef float f32x4 __attribute__((ext_vector_type(4)));

#define MFMA16(a,b,c) __builtin_amdgcn_mfma_f32_16x16x32_bf16((a),(b),(c),0,0,0)

#define ND 256
#define NQ 512
#define NF 50
#define L2E 1.44269504f
#define SHIFT 64.0f

// bf16-element offsets
#define SENT_E 0        // [52][264] sen^T; *rinv after pass1 (rows 50,51 zero)
#define QW3_E  13728    // [32][76]  q*w3*L2E + bias (cols 52..63 zero)
#define QG_E   16160    // [112][36] rows 0..49 q^T, rows 52..101 G^T
#define PD_E   20192    // [256][36] raw E
#define PQ_E   29408    // [32][264] raw E^T
#define SEN72_E 13728   // setup alias: sen[256][72]+bias
#define P1Q_E  13728    // pass-1 alias: 2 x [64][76]
#define PART_B 75712    // f32 [8][32] col partials
#define QTB_B  76736    // bf16 [512] qterm
#define RINV_B 77760    // f32 [256]
#define LDS_BYTES 78784 // x2 blocks = 157568 <= 163840

__launch_bounds__(512, 4)
__global__ void ca16_kernel(const float* __restrict__ query,
                            const float* __restrict__ doc,
                            const float* __restrict__ W,
                            float* __restrict__ out)
{
    extern __shared__ char smem[];
    bf16_t* lb = (bf16_t*)smem;
    float*  part  = (float*)(smem + PART_B);
    bf16_t* qtb   = (bf16_t*)(smem + QTB_B);
    float*  rinvf = (float*)(smem + RINV_B);

    const int tid = threadIdx.x;
    const int w = tid >> 6, l = tid & 63, ln = l & 15, lg = l >> 4;  // w: 0..7
    const int s = blockIdx.x;
    const float* sen_g = doc + (size_t)s * (ND * NF);
    const bf16x4 z4 = (bf16x4){(bf16_t)0.f,(bf16_t)0.f,(bf16_t)0.f,(bf16_t)0.f};

    auto stage_p1 = [&](int jt, int buf) {               // [64 j][76 f]
        const int j0 = jt * 64;
        bf16_t* dst = lb + P1Q_E + buf * 4864;
        for (int e = tid; e < 1664; e += 512) {
            int jj = e / 26, c = e - jj * 26;
            if (c < 25) {
                float2 v = ((const float2*)query)[(j0 + jj) * 25 + c];
                bf16x2 p;
                p[0] = (bf16_t)(v.x * W[100 + 2 * c] * L2E);
                p[1] = (bf16_t)(v.y * W[100 + 2 * c + 1] * L2E);
                *(bf16x2*)&dst[jj * 76 + 2 * c] = p;
            } else {
                bf16x2 p;
                p[0] = (bf16_t)((float)qtb[j0 + jj] * L2E);
                p[1] = (bf16_t)L2E;
                *(bf16x2*)&dst[jj * 76 + 50] = p;
            }
        }
    };
    auto stage_qw3 = [&](int jt) {                       // [32 j][76 f]
        const int j0 = jt * 32;
        for (int e = tid; e < 832; e += 512) {
            int jj = e / 26, c = e - jj * 26;
            if (c < 25) {
                float2 v = ((const float2*)query)[(j0 + jj) * 25 + c];
                bf16x2 p;
                p[0] = (bf16_t)(v.x * W[100 + 2 * c] * L2E);
                p[1] = (bf16_t)(v.y * W[100 + 2 * c + 1] * L2E);
                *(bf16x2*)&lb[QW3_E + jj * 76 + 2 * c] = p;
            } else {
                bf16x2 p;
                p[0] = (bf16_t)((float)qtb[j0 + jj] * L2E);
                p[1] = (bf16_t)L2E;
                *(bf16x2*)&lb[QW3_E + jj * 76 + 50] = p;
            }
        }
    };
    auto stage_qgq = [&](int jt) {                       // QG rows 0..49 = q^T
        const int j0 = jt * 32;
        for (int e = tid; e < 800; e += 512) {
            int c = e >> 5, jj = e & 31;
            float2 v = ((const float2*)query)[(j0 + jj) * 25 + c];
            lb[QG_E + (2 * c) * 36 + jj]     = (bf16_t)v.x;
            lb[QG_E + (2 * c + 1) * 36 + jj] = (bf16_t)v.y;
        }
    };

    // ---------------- setup 1 ----------------
    for (int e = tid; e < 132; e += 512) {               // SENT rows 50,51 zero
        int f = 50 + e / 66, c4 = (e - (e / 66) * 66) * 4;
        *(bf16x4*)&lb[SENT_E + f * 264 + c4] = z4;
    }
    for (int e = tid; e < 1280; e += 512) {              // SEN72 pad cols 52..71
        int i = e / 5, c4 = 52 + (e - (e / 5) * 5) * 4;
        *(bf16x4*)&lb[SEN72_E + i * 72 + c4] = z4;
    }
    for (int e = tid; e < 6400; e += 512) {              // doc -> SEN72 + SENT
        int i = e / 25, c = e - (e / 25) * 25;
        float2 v = ((const float2*)sen_g)[i * 25 + c];
        bf16x2 p; p[0] = (bf16_t)v.x; p[1] = (bf16_t)v.y;
        *(bf16x2*)&lb[SEN72_E + i * 72 + 2 * c] = p;
        lb[SENT_E + (2 * c) * 264 + i]     = p[0];
        lb[SENT_E + (2 * c + 1) * 264 + i] = p[1];
    }
    {                                                    // qterm (all 512 j)
        float acc = 0.f;
        #pragma unroll
        for (int c = 0; c < 25; ++c) {
            float2 v = ((const float2*)query)[tid * 25 + c];
            acc += v.x * W[NF + 2 * c] + v.y * W[NF + 2 * c + 1];
        }
        qtb[tid] = (bf16_t)acc;
    }
    if (tid < ND) {                                      // bias: 1, senw1
        float acc = 0.f;
        #pragma unroll
        for (int c = 0; c < 25; ++c) {
            float2 v = ((const float2*)sen_g)[tid * 25 + c];
            acc += v.x * W[2 * c] + v.y * W[2 * c + 1];
        }
        lb[SEN72_E + tid * 72 + 50] = (bf16_t)1.0f;
        lb[SEN72_E + tid * 72 + 51] = (bf16_t)acc;
    }
    __syncthreads();

    // ---------------- setup 2a: aS ----------------
    bf16x8 aS[2][2];
    #pragma unroll
    for (int mf = 0; mf < 2; ++mf)
        #pragma unroll
        for (int ks = 0; ks < 2; ++ks)
            aS[mf][ks] = *(bf16x8*)&lb[SEN72_E + (w * 32 + mf * 16 + ln) * 72 + lg * 8 + ks * 32];
    __syncthreads();

    // ---------------- setup 2b: P1Q pads + stage(0) ----------------
    for (int e = tid; e < 384; e += 512) {               // cols 52..63, both bufs
        int buf = e / 192, r = e - buf * 192;
        int jj = r / 3, c4 = 52 + (r - (r / 3) * 3) * 4;
        *(bf16x4*)&lb[P1Q_E + buf * 4864 + jj * 76 + c4] = z4;
    }
    stage_p1(0, 0);
    __syncthreads();

    // ---------------- pass 1: row sums ----------------
    float rpart[2][4] = {{0.f,0.f,0.f,0.f},{0.f,0.f,0.f,0.f}};
    for (int jt = 0; jt < 8; ++jt) {
        if (jt < 7) stage_p1(jt + 1, (jt + 1) & 1);
        const bf16_t* qb = lb + P1Q_E + (jt & 1) * 4864;
        f32x4 sacc[2][4];
        #pragma unroll
        for (int mf = 0; mf < 2; ++mf)
            #pragma unroll
            for (int nf = 0; nf < 4; ++nf)
                sacc[mf][nf] = (f32x4){-SHIFT, -SHIFT, -SHIFT, -SHIFT};
        #pragma unroll
        for (int ks = 0; ks < 2; ++ks)
            #pragma unroll
            for (int nf = 0; nf < 4; ++nf) {
                bf16x8 b = *(bf16x8*)&qb[(nf * 16 + ln) * 76 + lg * 8 + ks * 32];
                sacc[0][nf] = MFMA16(aS[0][ks], b, sacc[0][nf]);
                sacc[1][nf] = MFMA16(aS[1][ks], b, sacc[1][nf]);
            }
        #pragma unroll
        for (int mf = 0; mf < 2; ++mf)
            #pragma unroll
            for (int nf = 0; nf < 4; ++nf)
                #pragma unroll
                for (int r = 0; r < 4; ++r)
                    rpart[mf][r] += exp2f(sacc[mf][nf][r]);
        __syncthreads();
    }
    #pragma unroll
    for (int mf = 0; mf < 2; ++mf)
        #pragma unroll
        for (int r = 0; r < 4; ++r) {
            float v = rpart[mf][r];
            v += __shfl_xor(v, 1);
            v += __shfl_xor(v, 2);
            v += __shfl_xor(v, 4);
            v += __shfl_xor(v, 8);
            if (ln == 0) rinvf[w * 32 + mf * 16 + lg * 4 + r] = 1.f / v;
        }
    __syncthreads();

    // ---------------- transition ----------------
    for (int e = tid; e < 12800; e += 512) {             // SENT *= rinv (rows 0..49)
        int f = e / 256, i = e & 255;
        lb[SENT_E + f * 264 + i] = (bf16_t)((float)lb[SENT_E + f * 264 + i] * rinvf[i]);
    }
    for (int e = tid; e < 96; e += 512) {                // QW3 pad cols 52..63
        int jj = e / 3, c4 = 52 + (e - (e / 3) * 3) * 4;
        *(bf16x4*)&lb[QW3_E + jj * 76 + c4] = z4;
    }
    for (int e = tid; e < 108; e += 512) {               // QG pad rows 50,51,102..111
        int rr = e / 9, c4 = (e - (e / 9) * 9) * 4;
        int row = (rr < 2) ? (50 + rr) : (100 + rr);
        *(bf16x4*)&lb[QG_E + row * 36 + c4] = z4;
    }
    stage_qw3(0);
    __syncthreads();

    // ---------------- pass 2: 16 tiles, 2 barriers each ----------------
    f32x4 accQG[2][7];
    #pragma unroll
    for (int mf = 0; mf < 2; ++mf)
        #pragma unroll
        for (int nf = 0; nf < 7; ++nf) accQG[mf][nf] = (f32x4){0.f, 0.f, 0.f, 0.f};
    bf16x8 aPs[2];
    const int jf = w & 1, ff = w >> 1;
    const int fg = ff * 16 + ln;
    const int sent_row = SENT_E + (fg < 51 ? fg : 51) * 264;

    for (int jt = 0; jt < 16; ++jt) {
        // ---- region A: accQG(jt-1) + S(jt) ----
        if (jt > 0) {
            #pragma unroll
            for (int nf = 0; nf < 7; ++nf) {
                bf16x8 b = *(bf16x8*)&lb[QG_E + (nf * 16 + ln) * 36 + lg * 8];
                accQG[0][nf] = MFMA16(aPs[0], b, accQG[0][nf]);
                accQG[1][nf] = MFMA16(aPs[1], b, accQG[1][nf]);
            }
        }
        #pragma unroll
        for (int n2 = 0; n2 < 2; ++n2) {
            f32x4 sacc[2];
            sacc[0] = (f32x4){-SHIFT, -SHIFT, -SHIFT, -SHIFT};
            sacc[1] = (f32x4){-SHIFT, -SHIFT, -SHIFT, -SHIFT};
            #pragma unroll
            for (int ks = 0; ks < 2; ++ks) {
                bf16x8 b = *(bf16x8*)&lb[QW3_E + (n2 * 16 + ln) * 76 + lg * 8 + ks * 32];
                sacc[0] = MFMA16(aS[0][ks], b, sacc[0]);
                sacc[1] = MFMA16(aS[1][ks], b, sacc[1]);
            }
            #pragma unroll
            for (int mf = 0; mf < 2; ++mf)
                #pragma unroll
                for (int r = 0; r < 4; ++r)
                    sacc[mf][r] = exp2f(sacc[mf][r]);
            float cp = ((sacc[0][0] + sacc[0][1]) + (sacc[0][2] + sacc[0][3]))
                     + ((sacc[1][0] + sacc[1][1]) + (sacc[1][2] + sacc[1][3]));
            cp += __shfl_xor(cp, 16);
            cp += __shfl_xor(cp, 32);
            if (lg == 0) part[w * 32 + n2 * 16 + ln] = cp;
            #pragma unroll
            for (int mf = 0; mf < 2; ++mf) {
                bf16x4 pk;
                #pragma unroll
                for (int r = 0; r < 4; ++r) pk[r] = (bf16_t)sacc[mf][r];
                *(bf16x4*)&lb[PQ_E + (n2 * 16 + ln) * 264 + w * 32 + mf * 16 + lg * 4] = pk;
                #pragma unroll
                for (int r = 0; r < 4; ++r)
                    lb[PD_E + (w * 32 + mf * 16 + lg * 4 + r) * 36 + n2 * 16 + ln] = pk[r];
            }
        }
        __syncthreads();                                  // A

        // ---- region B: ci, aPs, G, staging ----
        float cs = 0.f;
        #pragma unroll
        for (int ww = 0; ww < 8; ++ww) cs += part[ww * 32 + (l & 31)];
        float civ = 1.f / cs;
        float cv[8];
        #pragma unroll
        for (int e = 0; e < 8; ++e) cv[e] = __shfl(civ, lg * 8 + e);
        #pragma unroll
        for (int mf = 0; mf < 2; ++mf) {
            bf16x8 raw = *(bf16x8*)&lb[PD_E + (w * 32 + mf * 16 + ln) * 36 + lg * 8];
            #pragma unroll
            for (int e = 0; e < 8; ++e)
                aPs[mf][e] = (bf16_t)((float)raw[e] * cv[e]);
        }
        {
            f32x4 g = (f32x4){0.f, 0.f, 0.f, 0.f};
            #pragma unroll
            for (int ks = 0; ks < 8; ++ks) {
                bf16x8 a = *(bf16x8*)&lb[PQ_E + (jf * 16 + ln) * 264 + ks * 32 + lg * 8];
                bf16x8 b = *(bf16x8*)&lb[sent_row + ks * 32 + lg * 8];
                g = MFMA16(a, b, g);
            }
            if (fg < 52) {
                bf16x4 gk;
                #pragma unroll
                for (int r = 0; r < 4; ++r) gk[r] = (bf16_t)g[r];
                *(bf16x4*)&lb[QG_E + (52 + fg) * 36 + jf * 16 + lg * 4] = gk;
            }
        }
        stage_qgq(jt);
        if (jt < 15) stage_qw3(jt + 1);
        __syncthreads();                                  // B
    }
    // final accQG (tile 15)
    #pragma unroll
    for (int nf = 0; nf < 7; ++nf) {
        bf16x8 b = *(bf16x8*)&lb[QG_E + (nf * 16 + ln) * 36 + lg * 8];
        accQG[0][nf] = MFMA16(aPs[0], b, accQG[0][nf]);
        accQG[1][nf] = MFMA16(aPs[1], b, accQG[1][nf]);
    }
    __syncthreads();

    // ---------------- epilogue ----------------
    float* ea = (float*)smem;                             // [256][56] f32
    #pragma unroll
    for (int mf = 0; mf < 2; ++mf)
        #pragma unroll
        for (int nf = 0; nf < 4; ++nf) {
            int f = nf * 16 + ln;
            if (f < 50)
                #pragma unroll
                for (int r = 0; r < 4; ++r)
                    ea[(w * 32 + mf * 16 + lg * 4 + r) * 56 + f] = accQG[mf][nf][r];
        }
    __syncthreads();
    const size_t ob0 = (size_t)s * (ND * 200);
    for (int v = tid; v < 6400; v += 512) {
        int i = v / 25, c = v - (v / 25) * 25, f = 2 * c;
        *(float2*)&out[ob0 + (size_t)i * 200 + f] = *(const float2*)&sen_g[i * 50 + f];
    }
    for (int v = tid; v < 6400; v += 512) {
        int i = v / 25, c = v - (v / 25) * 25, f = 2 * c;
        float2 o;
        o.x = ea[i * 56 + f]; o.y = ea[i * 56 + f + 1];
        *(float2*)&out[ob0 + (size_t)i * 200 + 50 + f] = o;
    }
    for (int v = tid; v < 6400; v += 512) {
        int i = v / 25, c = v - (v / 25) * 25, f = 2 * c;
        float2 d = *(const float2*)&sen_g[i * 50 + f];
        float2 o;
        o.x = d.x * ea[i * 56 + f]; o.y = d.y * ea[i * 56 + f + 1];
        *(float2*)&out[ob0 + (size_t)i * 200 + 100 + f] = o;
    }
    __syncthreads();
    #pragma unroll
    for (int mf = 0; mf < 2; ++mf)
        #pragma unroll
        for (int nf = 3; nf < 7; ++nf) {
            int qf = nf * 16 + ln - 52;
            if (qf >= 0 && qf < 50)
                #pragma unroll
                for (int r = 0; r < 4; ++r)
                    ea[(w * 32 + mf * 16 + lg * 4 + r) * 56 + qf] = accQG[mf][nf][r];
        }
    __syncthreads();
    for (int v = tid; v < 6400; v += 512) {
        int i = v / 25, c = v - (v / 25) * 25, f = 2 * c;
        float2 d = *(const float2*)&sen_g[i * 50 + f];
        float2 o;
        o.x = d.x * ea[i * 56 + f]; o.y = d.y * ea[i * 56 + f + 1];
        *(float2*)&out[ob0 + (size_t)i * 200 + 150 + f] = o;
    }
}

extern "C" void kernel_launch(void* const* d_in, const int* in_sizes, int n_in,
                              void* d_out, int out_size, void* d_ws, size_t ws_size,
                              hipStream_t stream) {
    const float* query = (const float*)d_in[0];
    const float* doc   = (const float*)d_in[1];
    const float* W     = (const float*)d_in[2];
    float* out = (float*)d_out;
    (void)d_ws; (void)ws_size; (void)n_in; (void)in_sizes; (void)out_size;

    hipFuncSetAttribute((const void*)ca16_kernel,
                        hipFuncAttributeMaxDynamicSharedMemorySize,
                        LDS_BYTES);
    ca16_kernel<<<dim3(512), dim3(512), LDS_BYTES, stream>>>(query, doc, W, out);
}

// Round 17
// 143.309 us; speedup vs baseline: 1.5074x; 1.5074x over previous
//
#include <hip/hip_runtime.h>
#include <math.h>

typedef __bf16 bf16_t;
typedef bf16_t bf16x2 __attribute__((ext_vector_type(2)));
typedef bf16_t bf16x4 __attribute__((ext_vector_type(4)));
typedef bf16_t bf16x8 __attribute__((ext_vector_type(8)));
typedef float f32x4 __attribute__((ext_vector_type(4)));

#define MFMA16(a,b,c) __builtin_amdgcn_mfma_f32_16x16x32_bf16((a),(b),(c),0,0,0)

#define ND 256
#define NQ 512
#define NF 50
#define L2E 1.44269504f
#define SHIFT 64.0f

// bf16-element offsets
#define SENT_E 0        // [64 f][264 i]  sen^T raw (rows 50..63 zero)
#define PD0_E  16896    // [256 i][72 j]  raw-E buf0 (setup alias: sen[i][72f]+bias)
#define PD1_E  35328    // [256 i][72 j]  raw-E buf1
#define QW3_E  53760    // 2 x [64 j][72 f]
#define QTT_E  62976    // 2 x [64 f][72 j] raw q^T
#define KL0_E  16896    // epilogue chunk buf0 [256][40] bf16
#define KL1_E  27136    // chunk buf1
#define EA_B   74752    // epilogue accD f32 [256][68]
#define PART_B  144384  // f32 [16 w][64 j] col partials
#define STATS_B 148480  // f32: qterm[512], ci[64], rinv[256]
#define LDS_BYTES 151808

#define ST_QTERM 0
#define ST_CI    512
#define ST_RINV  576

__launch_bounds__(1024, 4)
__global__ void ca17_kernel(const float* __restrict__ query,
                            const float* __restrict__ doc,
                            const float* __restrict__ W,
                            float* __restrict__ out)
{
    extern __shared__ char smem[];
    bf16_t* lb = (bf16_t*)smem;
    float* part  = (float*)(smem + PART_B);
    float* stats = (float*)(smem + STATS_B);

    const int tid = threadIdx.x;
    const int w = tid >> 6, l = tid & 63, ln = l & 15, lg = l >> 4;
    const int s = blockIdx.x;
    const float* sen_g = doc + (size_t)s * (ND * NF);

    auto stageQW3 = [&](int jt, int buf, int tbase, int tn) {
        const int j0 = jt * 64;
        bf16_t* dst = lb + QW3_E + buf * 4608;
        for (int e = tid - tbase; e < 1664; e += tn) {
            int jj = e / 26, c = e - jj * 26;
            if (c < 25) {
                float2 v = ((const float2*)query)[(j0 + jj) * 25 + c];
                bf16x2 p;
                p[0] = (bf16_t)(v.x * W[100 + 2 * c] * L2E);
                p[1] = (bf16_t)(v.y * W[100 + 2 * c + 1] * L2E);
                *(bf16x2*)&dst[jj * 72 + 2 * c] = p;
            } else {
                bf16x2 p;
                p[0] = (bf16_t)(stats[ST_QTERM + j0 + jj] * L2E);
                p[1] = (bf16_t)L2E;
                *(bf16x2*)&dst[jj * 72 + 50] = p;
            }
        }
    };
    auto stageQTT = [&](int jt, int buf, int tbase, int tn) {  // raw q^T
        const int j0 = jt * 64;
        bf16_t* dst = lb + QTT_E + buf * 4608;
        for (int e = tid - tbase; e < 1600; e += tn) {
            int c = e >> 6, jj = e & 63;
            float2 v = ((const float2*)query)[(j0 + jj) * 25 + c];
            dst[(2 * c) * 72 + jj]     = (bf16_t)v.x;
            dst[(2 * c + 1) * 72 + jj] = (bf16_t)v.y;
        }
    };

    // ---------------- setup phase 1 ----------------
    for (int e = tid; e < 924; e += 1024) {               // SENT pad rows 50..63
        int f = 50 + e / 66, c4 = (e - (e / 66) * 66) * 4;
        *(bf16x4*)&lb[SENT_E + f * 264 + c4] = (bf16x4){(bf16_t)0.f,(bf16_t)0.f,(bf16_t)0.f,(bf16_t)0.f};
    }
    for (int e = tid; e < 768; e += 1024) {               // sen K-pad cols 52..63
        int i = e / 3, c4 = 52 + (e - (e / 3) * 3) * 4;
        *(bf16x4*)&lb[PD0_E + i * 72 + c4] = (bf16x4){(bf16_t)0.f,(bf16_t)0.f,(bf16_t)0.f,(bf16_t)0.f};
    }
    for (int e = tid; e < 384; e += 1024) {               // QW3 pad cols (both bufs)
        int b = e / 192, r = e - b * 192;
        int jj = r / 3, c4 = 52 + (r - (r / 3) * 3) * 4;
        *(bf16x4*)&lb[QW3_E + b * 4608 + jj * 72 + c4] = (bf16x4){(bf16_t)0.f,(bf16_t)0.f,(bf16_t)0.f,(bf16_t)0.f};
    }
    for (int e = tid; e < 504; e += 1024) {               // QTT pad rows (both bufs)
        int b = e / 252, r = e - b * 252;
        int f = 50 + r / 18, c4 = (r - (r / 18) * 18) * 4;
        *(bf16x4*)&lb[QTT_E + b * 4608 + f * 72 + c4] = (bf16x4){(bf16_t)0.f,(bf16_t)0.f,(bf16_t)0.f,(bf16_t)0.f};
    }
    for (int e = tid; e < 256 * 25; e += 1024) {          // doc -> sen[i][f] + sen^T
        int i = e / 25, c = e - i * 25;
        float2 v = ((const float2*)sen_g)[i * 25 + c];
        bf16x2 p; p[0] = (bf16_t)v.x; p[1] = (bf16_t)v.y;
        *(bf16x2*)&lb[PD0_E + i * 72 + 2 * c] = p;
        lb[SENT_E + (2 * c) * 264 + i]     = p[0];
        lb[SENT_E + (2 * c + 1) * 264 + i] = p[1];
    }
    if (tid < NQ) {                                       // qterm = q . w2
        float acc = 0.f;
        #pragma unroll
        for (int c = 0; c < 25; ++c) {
            float2 v = ((const float2*)query)[tid * 25 + c];
            acc += v.x * W[NF + 2 * c] + v.y * W[NF + 2 * c + 1];
        }
        stats[ST_QTERM + tid] = acc;
    }
    if (tid < ND) {                                       // bias cols: 1, senw1
        float acc = 0.f;
        #pragma unroll
        for (int c = 0; c < 25; ++c) {
            float2 v = ((const float2*)sen_g)[tid * 25 + c];
            acc += v.x * W[2 * c] + v.y * W[2 * c + 1];
        }
        lb[PD0_E + tid * 72 + 50] = (bf16_t)1.0f;
        lb[PD0_E + tid * 72 + 51] = (bf16_t)acc;
    }
    __syncthreads();

    // ---------------- setup phase 2 ----------------
    bf16x8 aS[2];
    #pragma unroll
    for (int ks = 0; ks < 2; ++ks)
        aS[ks] = *(bf16x8*)&lb[PD0_E + (w * 16 + ln) * 72 + lg * 8 + ks * 32];
    stageQW3(0, 0, 0, 1024);
    stageQTT(0, 0, 0, 1024);
    __syncthreads();

    // ---------------- single fused pass, symmetric K ----------------
    f32x4 accD[4];
    f32x4 K[9];                       // block cb=(w+d)&15, d=0..8 (d=8 iff w<8)
    #pragma unroll
    for (int nf = 0; nf < 4; ++nf) accD[nf] = (f32x4){0.f, 0.f, 0.f, 0.f};
    #pragma unroll
    for (int d = 0; d < 9; ++d) K[d] = (f32x4){0.f, 0.f, 0.f, 0.f};
    float rpart[4] = {0.f, 0.f, 0.f, 0.f};

    auto consumeTile = [&](const bf16_t* pdp, const bf16_t* qtp) {
        bf16x8 aPs[2];
        #pragma unroll
        for (int ks = 0; ks < 2; ++ks) {
            bf16x8 raw = *(bf16x8*)&pdp[(w * 16 + ln) * 72 + lg * 8 + ks * 32];
            float4 c0 = *(const float4*)&stats[ST_CI + lg * 8 + ks * 32];
            float4 c1 = *(const float4*)&stats[ST_CI + lg * 8 + ks * 32 + 4];
            aPs[ks][0] = (bf16_t)((float)raw[0] * c0.x);
            aPs[ks][1] = (bf16_t)((float)raw[1] * c0.y);
            aPs[ks][2] = (bf16_t)((float)raw[2] * c0.z);
            aPs[ks][3] = (bf16_t)((float)raw[3] * c0.w);
            aPs[ks][4] = (bf16_t)((float)raw[4] * c1.x);
            aPs[ks][5] = (bf16_t)((float)raw[5] * c1.y);
            aPs[ks][6] = (bf16_t)((float)raw[6] * c1.z);
            aPs[ks][7] = (bf16_t)((float)raw[7] * c1.w);
        }
        #pragma unroll
        for (int ks = 0; ks < 2; ++ks)
            #pragma unroll
            for (int nf = 0; nf < 4; ++nf) {
                bf16x8 bq = *(bf16x8*)&qtp[(nf * 16 + ln) * 72 + lg * 8 + ks * 32];
                accD[nf] = MFMA16(aPs[ks], bq, accD[nf]);
            }
        #pragma unroll
        for (int d = 0; d < 9; ++d) {
            if (d < 8 || w < 8) {
                const int cb = (w + d) & 15;
                #pragma unroll
                for (int ks = 0; ks < 2; ++ks) {
                    bf16x8 bb = *(bf16x8*)&pdp[(cb * 16 + ln) * 72 + lg * 8 + ks * 32];
                    K[d] = MFMA16(aPs[ks], bb, K[d]);
                }
            }
        }
    };

    for (int jt = 0; jt < 8; ++jt) {
        if (jt > 0) {
            const int pb = (jt - 1) & 1;
            consumeTile(lb + (pb ? PD1_E : PD0_E), lb + QTT_E + pb * 4608);
        }

        // -------- S(jt) -> raw E -> pd + col partials --------
        const bf16_t* qb = lb + QW3_E + (jt & 1) * 4608;
        bf16_t* pd = lb + ((jt & 1) ? PD1_E : PD0_E);
        f32x4 acc[4];
        #pragma unroll
        for (int nf = 0; nf < 4; ++nf) acc[nf] = (f32x4){-SHIFT, -SHIFT, -SHIFT, -SHIFT};
        #pragma unroll
        for (int ks = 0; ks < 2; ++ks)
            #pragma unroll
            for (int nf = 0; nf < 4; ++nf) {
                bf16x8 b = *(bf16x8*)&qb[(nf * 16 + ln) * 72 + lg * 8 + ks * 32];
                acc[nf] = MFMA16(aS[ks], b, acc[nf]);
            }
        #pragma unroll
        for (int nf = 0; nf < 4; ++nf) {
            #pragma unroll
            for (int r = 0; r < 4; ++r) acc[nf][r] = exp2f(acc[nf][r]);
            float cp = (acc[nf][0] + acc[nf][1]) + (acc[nf][2] + acc[nf][3]);
            cp += __shfl_xor(cp, 16);
            cp += __shfl_xor(cp, 32);
            if (lg == 0) part[w * 64 + nf * 16 + ln] = cp;
            #pragma unroll
            for (int r = 0; r < 4; ++r) {
                rpart[r] += acc[nf][r];
                pd[(w * 16 + lg * 4 + r) * 72 + nf * 16 + ln] = (bf16_t)acc[nf][r];
            }
        }
        __syncthreads();                                  // A: pd + partials visible

        if (w == 0) {
            float cs = 0.f;
            #pragma unroll
            for (int ww = 0; ww < 16; ++ww) cs += part[ww * 64 + l];
            stats[ST_CI + l] = 1.f / cs;
        } else if (jt < 7) {
            stageQW3(jt + 1, (jt + 1) & 1, 64, 960);
            stageQTT(jt + 1, (jt + 1) & 1, 64, 960);
        }
        __syncthreads();                                  // B: ci + staged bufs
    }
    consumeTile(lb + PD1_E, lb + QTT_E + 4608);           // final consume (tile 7)

    // ---------------- rinv ----------------
    #pragma unroll
    for (int r = 0; r < 4; ++r) {
        float v = rpart[r];
        v += __shfl_xor(v, 1);
        v += __shfl_xor(v, 2);
        v += __shfl_xor(v, 4);
        v += __shfl_xor(v, 8);
        if (ln == 0) stats[ST_RINV + w * 16 + lg * 4 + r] = 1.f / v;
    }
    __syncthreads();                                      // PD/QTT dead, rinv visible

    // accD -> ea early (frees accumulators before accQ phase)
    float* ea = (float*)(smem + EA_B);                    // [256][68]
    #pragma unroll
    for (int nf = 0; nf < 4; ++nf)
        #pragma unroll
        for (int r = 0; r < 4; ++r)
            ea[(w * 16 + lg * 4 + r) * 68 + nf * 16 + ln] = accD[nf][r];

    // ---------------- aQ2D = (ri*K) @ sen^T, 8 chunks, symmetric fill -----
    f32x4 accQ[4];
    #pragma unroll
    for (int nf = 0; nf < 4; ++nf) accQ[nf] = (f32x4){0.f, 0.f, 0.f, 0.f};
    #pragma unroll
    for (int kt = 0; kt < 8; ++kt) {
        bf16_t* kl = lb + ((kt & 1) ? KL1_E : KL0_E);
        // direct blocks (w, cb) with cb in this chunk
        #pragma unroll
        for (int d = 0; d < 9; ++d) {
            if (d < 8 || w < 8) {
                const int cb = (w + d) & 15;
                if ((cb >> 1) == kt) {
                    const int h = cb & 1;
                    const float riv = stats[ST_RINV + cb * 16 + ln];
                    #pragma unroll
                    for (int r = 0; r < 4; ++r)
                        kl[(w * 16 + lg * 4 + r) * 40 + h * 16 + ln] =
                            (bf16_t)(K[d][r] * riv);
                }
            }
        }
        // transposed blocks (cb, w): this wave's column lands in chunk w>>1
        if ((w >> 1) == kt) {
            const int h = w & 1;
            float4 rv = *(const float4*)&stats[ST_RINV + w * 16 + lg * 4];
            #pragma unroll
            for (int d = 1; d < 9; ++d) {
                if (d < 8 || w < 8) {
                    const int cb = (w + d) & 15;
                    bf16x4 pk;
                    pk[0] = (bf16_t)(K[d][0] * rv.x);
                    pk[1] = (bf16_t)(K[d][1] * rv.y);
                    pk[2] = (bf16_t)(K[d][2] * rv.z);
                    pk[3] = (bf16_t)(K[d][3] * rv.w);
                    *(bf16x4*)&kl[(cb * 16 + ln) * 40 + h * 16 + lg * 4] = pk;
                }
            }
        }
        __syncthreads();
        bf16x8 aK = *(bf16x8*)&kl[(w * 16 + ln) * 40 + lg * 8];
        #pragma unroll
        for (int nf = 0; nf < 4; ++nf) {
            bf16x8 b = *(bf16x8*)&lb[SENT_E + (nf * 16 + ln) * 264 + kt * 32 + lg * 8];
            accQ[nf] = MFMA16(aK, b, accQ[nf]);
        }
    }
    __syncthreads();                                      // SENT/KL dead

    // ---------------- epilogue (fully-contiguous streaming writes) --------
    float* eb = (float*)smem;                             // [256][68]
    #pragma unroll
    for (int nf = 0; nf < 4; ++nf)
        #pragma unroll
        for (int r = 0; r < 4; ++r)
            eb[(w * 16 + lg * 4 + r) * 68 + nf * 16 + ln] = accQ[nf][r];
    __syncthreads();
    float2* outv = (float2*)(out + (size_t)s * (ND * 200));
    for (int v = tid; v < 25600; v += 1024) {
        int i = v / 100, p = v - (v / 100) * 100;
        int sg = p / 25, c = p - sg * 25, f = 2 * c;
        float2 o;
        if (sg == 0) {
            o = *(const float2*)&sen_g[i * 50 + f];
        } else if (sg == 1) {
            o.x = ea[i * 68 + f]; o.y = ea[i * 68 + f + 1];
        } else if (sg == 2) {
            float2 d = *(const float2*)&sen_g[i * 50 + f];
            o.x = d.x * ea[i * 68 + f]; o.y = d.y * ea[i * 68 + f + 1];
        } else {
            float2 d = *(const float2*)&sen_g[i * 50 + f];
            o.x = d.x * eb[i * 68 + f]; o.y = d.y * eb[i * 68 + f + 1];
        }
        outv[v] = o;
    }
}

extern "C" void kernel_launch(void* const* d_in, const int* in_sizes, int n_in,
                              void* d_out, int out_size, void* d_ws, size_t ws_size,
                              hipStream_t stream) {
    const float* query = (const float*)d_in[0];
    const float* doc   = (const float*)d_in[1];
    const float* W     = (const float*)d_in[2];
    float* out = (float*)d_out;
    (void)d_ws; (void)ws_size; (void)n_in; (void)in_sizes; (void)out_size;

    hipFuncSetAttribute((const void*)ca17_kernel,
                        hipFuncAttributeMaxDynamicSharedMemorySize,
                        LDS_BYTES);
    ca17_kernel<<<dim3(512), dim3(1024), LDS_BYTES, stream>>>(query, doc, W, out);
}